// Round 3
// baseline (674.788 us; speedup 1.0000x reference)
//
#include <hip/hip_runtime.h>

#define LOG2E 1.44269504088896340736f
#define QSCALE 0.18033688011112042f  // 0.125 * LOG2E

typedef __attribute__((ext_vector_type(8))) short bf16x8;
typedef __attribute__((ext_vector_type(4))) float f32x4;

__device__ __forceinline__ unsigned short f2b(float f) {
  union { float f; unsigned int u; } x; x.f = f;
  return (unsigned short)((x.u + 0x8000u) >> 16);
}

// pack two fp32 -> two bf16 in 3 VALU ops
__device__ __forceinline__ unsigned int pk_bf16(float a, float b) {
  union { float f; unsigned int u; } xa, xb; xa.f = a; xb.f = b;
  return __builtin_amdgcn_perm(xb.u + 0x8000u, xa.u + 0x8000u, 0x07060302);
}

__device__ __forceinline__ void gld_lds16(const void* g, void* l) {
  __builtin_amdgcn_global_load_lds((const __attribute__((address_space(1))) void*)g,
                                   (__attribute__((address_space(3))) void*)l,
                                   16, 0, 0);
}

// ---------------- elementwise fp32 -> bf16 cast (x, y) ----------------
__global__ __launch_bounds__(256) void cast4(const float* __restrict__ in,
                                             unsigned short* __restrict__ out, int n4) {
  int i = blockIdx.x * 256 + threadIdx.x;
  if (i < n4) {
    float4 v = ((const float4*)in)[i];
    uint2 o;
    o.x = pk_bf16(v.x, v.y);
    o.y = pk_bf16(v.z, v.w);
    ((uint2*)out)[i] = o;
  }
}

// ---------------- mask pre-scale: out = mask * log2(e), fp32 ----------------
__global__ __launch_bounds__(256) void scale_mask(const float* __restrict__ in,
                                                  float* __restrict__ out, int n4) {
  int i = blockIdx.x * 256 + threadIdx.x;
  if (i < n4) {
    f32x4 v = ((const f32x4*)in)[i];
    ((f32x4*)out)[i] = v * LOG2E;
  }
}

// ---------------- transpose + cast: W (K x N) fp32 -> Wt (N x K) bf16 ----------------
__global__ __launch_bounds__(256) void transpose_cast(const float* __restrict__ W,
                                                      unsigned short* __restrict__ Wt,
                                                      int K, int N) {
  __shared__ float t[32][33];
  int j = threadIdx.x & 31, i0 = threadIdx.x >> 5;
  int nb = blockIdx.x * 32, kb = blockIdx.y * 32;
  #pragma unroll
  for (int p = 0; p < 4; ++p) {
    int i = i0 + p * 8;
    t[i][j] = W[(size_t)(kb + i) * N + nb + j];
  }
  __syncthreads();
  #pragma unroll
  for (int p = 0; p < 4; ++p) {
    int i = i0 + p * 8;
    Wt[(size_t)(nb + i) * K + kb + j] = f2b(t[j][i]);
  }
}

// ---------------- GEMM: C(MxN) = A(MxK) @ Bt(NxK)^T + bias ----------------
// MODE 0: fp32 C out. MODE 1: kv -> K[b,h,s,64] + Vt[b,h,64,s]. MODE 2: q -> Q[b,h,s,64] * QSCALE.
template <int MODE>
__global__ __launch_bounds__(256)
void gemm128(const unsigned short* __restrict__ A,
             const unsigned short* __restrict__ Bt,
             const float* __restrict__ bias,
             void* __restrict__ out0, void* __restrict__ out1,
             int M, int N, int K) {
  __shared__ __align__(16) unsigned short As[128 * 64];
  __shared__ __align__(16) unsigned short Bs[128 * 64];
  const int tid = threadIdx.x;
  const int bn = blockIdx.x, bm = blockIdx.y;
  const int wave = tid >> 6, lane = tid & 63;
  const int wm = (wave >> 1) * 64, wn = (wave & 1) * 64;
  const int lrow = lane & 15, lk = (lane >> 4) * 8;
  const int quad = lane >> 4;

  f32x4 acc[4][4];
  #pragma unroll
  for (int i = 0; i < 4; ++i)
    #pragma unroll
    for (int j = 0; j < 4; ++j)
      #pragma unroll
      for (int r = 0; r < 4; ++r) acc[i][j][r] = 0.f;

  const unsigned short* Ab = A + (size_t)(bm * 128) * K;
  const unsigned short* Bb = Bt + (size_t)(bn * 128) * K;

  for (int k0 = 0; k0 < K; k0 += 64) {
    #pragma unroll
    for (int i = 0; i < 4; ++i) {
      int e = i * 256 + tid;
      int row = e >> 3, c16 = e & 7;
      gld_lds16(Ab + (size_t)row * K + k0 + c16 * 8, &As[e * 8]);
    }
    #pragma unroll
    for (int i = 0; i < 4; ++i) {
      int e = i * 256 + tid;
      int row = e >> 3, c16 = e & 7;
      gld_lds16(Bb + (size_t)row * K + k0 + c16 * 8, &Bs[e * 8]);
    }
    __builtin_amdgcn_s_waitcnt(0);
    __syncthreads();
    #pragma unroll
    for (int ks = 0; ks < 2; ++ks) {
      bf16x8 af[4], bf[4];
      #pragma unroll
      for (int i = 0; i < 4; ++i)
        af[i] = *(const bf16x8*)&As[(wm + i * 16 + lrow) * 64 + ks * 32 + lk];
      #pragma unroll
      for (int j = 0; j < 4; ++j)
        bf[j] = *(const bf16x8*)&Bs[(wn + j * 16 + lrow) * 64 + ks * 32 + lk];
      #pragma unroll
      for (int i = 0; i < 4; ++i)
        #pragma unroll
        for (int j = 0; j < 4; ++j)
          acc[i][j] = __builtin_amdgcn_mfma_f32_16x16x32_bf16(af[i], bf[j], acc[i][j], 0, 0, 0);
    }
    __syncthreads();
  }

  const int col0 = bn * 128 + wn;  // wave-uniform 64-col range
  #pragma unroll
  for (int i = 0; i < 4; ++i) {
    const int row0 = bm * 128 + wm + i * 16 + quad * 4;
    const int b = row0 >> 11, s0 = row0 & 2047;
    #pragma unroll
    for (int j = 0; j < 4; ++j) {
      const int cc = j * 16 + lrow;
      const float bv = bias[col0 + cc];
      float v0 = acc[i][j][0] + bv, v1 = acc[i][j][1] + bv;
      float v2 = acc[i][j][2] + bv, v3 = acc[i][j][3] + bv;
      if (MODE == 0) {
        float* C = (float*)out0;
        size_t off = (size_t)row0 * N + col0 + cc;
        C[off] = v0; C[off + N] = v1; C[off + 2 * N] = v2; C[off + 3 * N] = v3;
      } else if (MODE == 1) {
        const int h = col0 >> 7;
        if ((col0 & 64) == 0) {  // K half: K[b,h,s,64]
          unsigned short* Kb = (unsigned short*)out0;
          size_t base = ((size_t)(b * 16 + h) * 2048 + s0) * 64 + cc;
          Kb[base] = f2b(v0); Kb[base + 64] = f2b(v1);
          Kb[base + 128] = f2b(v2); Kb[base + 192] = f2b(v3);
        } else {                 // V half: Vt[b,h,64,s]
          unsigned short* Vt = (unsigned short*)out1;
          size_t base = ((size_t)(b * 16 + h) * 64 + cc) * 2048 + s0;
          uint2 p; p.x = pk_bf16(v0, v1); p.y = pk_bf16(v2, v3);
          *(uint2*)&Vt[base] = p;
        }
      } else {  // MODE 2: Q[b,h,s,64], pre-scaled by 0.125*log2e
        v0 *= QSCALE; v1 *= QSCALE; v2 *= QSCALE; v3 *= QSCALE;
        const int h = col0 >> 6;
        unsigned short* Qb = (unsigned short*)out0;
        size_t base = ((size_t)(b * 16 + h) * 2048 + s0) * 64 + cc;
        Qb[base] = f2b(v0); Qb[base + 64] = f2b(v1);
        Qb[base + 128] = f2b(v2); Qb[base + 192] = f2b(v3);
      }
    }
  }
}

// ---------------- flash attention v3: barrier-free, direct-global fragments ----
// grid 1024 linear; swizzled so the 16 qt-blocks of each (b,h) land on one XCD.
// 4 waves of 32 q-cols each. S^T = K Q^T (Q pre-scaled, mask pre-scaled as MFMA C-init),
// exp2 without max-tracking, P roundtrip through wave-private LDS (pitch 72), O^T = V^T P^T.
__global__ __launch_bounds__(256)
void attn(const unsigned short* __restrict__ Qbuf,
          const unsigned short* __restrict__ Kbuf,
          const unsigned short* __restrict__ Vtbuf,
          const float* __restrict__ masks,   // mask * log2e, fp32
          unsigned short* __restrict__ vals) {
  const int linear = blockIdx.x;
  const int xcd = linear & 7, slot = linear >> 3;
  const int qt = slot & 15, hbi = slot >> 4;
  const int hb = xcd * 8 + hbi;          // all 16 qt of this (b,h) share an XCD
  const int b = hb >> 4, h = hb & 15;
  const int tid = threadIdx.x, lane = tid & 63, w = tid >> 6;
  const int lrow = lane & 15, quad = lane >> 4;

  __shared__ __align__(16) unsigned short Ps[128 * 72];  // wave-private rows

  const unsigned short* qp = Qbuf + ((size_t)(b * 16 + h) * 2048 + qt * 128) * 64;
  const unsigned short* kp = Kbuf + (size_t)(b * 16 + h) * 2048 * 64;
  const unsigned short* vp = Vtbuf + (size_t)(b * 16 + h) * 64 * 2048;
  const float* mp = masks + (size_t)(qt * 128 + w * 32) * 2048;

  // Q fragments (B-operand: n=q, k=d) — direct 16B global loads
  bf16x8 qf[2][2];
  #pragma unroll
  for (int iq = 0; iq < 2; ++iq)
    #pragma unroll
    for (int ks = 0; ks < 2; ++ks)
      qf[iq][ks] = *(const bf16x8*)(qp + (size_t)(w * 32 + iq * 16 + lrow) * 64 + ks * 32 + quad * 8);

  f32x4 o_acc[4][2];  // O^T: d = id*16+quad*4+r, q = iq*16+lrow
  #pragma unroll
  for (int id = 0; id < 4; ++id)
    #pragma unroll
    for (int iq = 0; iq < 2; ++iq)
      #pragma unroll
      for (int r = 0; r < 4; ++r) o_acc[id][iq][r] = 0.f;
  float lsum[2] = {0.f, 0.f};

  for (int kt = 0; kt < 32; ++kt) {
    // K fragments (A-operand: m=key, k=d) — direct 16B global loads
    bf16x8 kf[2][4];
    #pragma unroll
    for (int ks = 0; ks < 2; ++ks)
      #pragma unroll
      for (int ik = 0; ik < 4; ++ik)
        kf[ks][ik] = *(const bf16x8*)(kp + (size_t)(kt * 64 + ik * 16 + lrow) * 64 + ks * 32 + quad * 8);

    // z init = pre-scaled mask (MFMA C operand), nontemporal to spare L1
    f32x4 z[4][2];
    #pragma unroll
    for (int ik = 0; ik < 4; ++ik)
      #pragma unroll
      for (int iq = 0; iq < 2; ++iq)
        z[ik][iq] = __builtin_nontemporal_load(
            (const f32x4*)(mp + (size_t)(iq * 16 + lrow) * 2048 + kt * 64 + ik * 16 + quad * 4));

    // S^T = K (Q*c1)^T + mask*log2e   (exp2 domain)
    #pragma unroll
    for (int ks = 0; ks < 2; ++ks)
      #pragma unroll
      for (int ik = 0; ik < 4; ++ik)
        #pragma unroll
        for (int iq = 0; iq < 2; ++iq)
          z[ik][iq] = __builtin_amdgcn_mfma_f32_16x16x32_bf16(kf[ks][ik], qf[iq][ks], z[ik][iq], 0, 0, 0);

    // exp2, accumulate l partials, pack P^T -> wave-private LDS rows (pitch 72)
    #pragma unroll
    for (int ik = 0; ik < 4; ++ik)
      #pragma unroll
      for (int iq = 0; iq < 2; ++iq) {
        float e0 = exp2f(z[ik][iq][0]), e1 = exp2f(z[ik][iq][1]);
        float e2 = exp2f(z[ik][iq][2]), e3 = exp2f(z[ik][iq][3]);
        lsum[iq] += (e0 + e1) + (e2 + e3);
        uint2 p;
        p.x = pk_bf16(e0, e1);
        p.y = pk_bf16(e2, e3);
        *(uint2*)&Ps[(w * 32 + iq * 16 + lrow) * 72 + ik * 16 + quad * 4] = p;
      }
    __builtin_amdgcn_s_waitcnt(0xC07F);  // lgkmcnt(0): our Ps writes -> our reads

    // O^T += V^T P^T ; V fragments direct from global (A-operand: m=d, k=key)
    #pragma unroll
    for (int ks = 0; ks < 2; ++ks) {
      bf16x8 vf[4], pf[2];
      #pragma unroll
      for (int id = 0; id < 4; ++id)
        vf[id] = *(const bf16x8*)(vp + (size_t)(id * 16 + lrow) * 2048 + kt * 64 + ks * 32 + quad * 8);
      #pragma unroll
      for (int iq = 0; iq < 2; ++iq)
        pf[iq] = *(const bf16x8*)&Ps[(w * 32 + iq * 16 + lrow) * 72 + ks * 32 + quad * 8];
      #pragma unroll
      for (int id = 0; id < 4; ++id)
        #pragma unroll
        for (int iq = 0; iq < 2; ++iq)
          o_acc[id][iq] = __builtin_amdgcn_mfma_f32_16x16x32_bf16(vf[id], pf[iq], o_acc[id][iq], 0, 0, 0);
    }
  }

  // final l reduction across quads, then normalize + store O^T
  unsigned short* ob = vals + (size_t)(b * 2048 + qt * 128 + w * 32) * 1024 + h * 64;
  #pragma unroll
  for (int iq = 0; iq < 2; ++iq) {
    float s = lsum[iq];
    s += __shfl_xor(s, 16);
    s += __shfl_xor(s, 32);
    float inv = 1.f / s;
    #pragma unroll
    for (int id = 0; id < 4; ++id) {
      uint2 p;
      p.x = pk_bf16(o_acc[id][iq][0] * inv, o_acc[id][iq][1] * inv);
      p.y = pk_bf16(o_acc[id][iq][2] * inv, o_acc[id][iq][3] * inv);
      *(uint2*)&ob[(size_t)(iq * 16 + lrow) * 1024 + id * 16 + quad * 4] = p;
    }
  }
}

extern "C" void kernel_launch(void* const* d_in, const int* in_sizes, int n_in,
                              void* d_out, int out_size, void* d_ws, size_t ws_size,
                              hipStream_t stream) {
  const float* x    = (const float*)d_in[0];
  const float* y    = (const float*)d_in[1];
  const float* mask = (const float*)d_in[2];
  const float* Wkv  = (const float*)d_in[3];
  const float* bkv  = (const float*)d_in[4];
  const float* Wq   = (const float*)d_in[5];
  const float* bq   = (const float*)d_in[6];
  const float* Wo   = (const float*)d_in[7];
  const float* bo   = (const float*)d_in[8];

  char* ws = (char*)d_ws;
  unsigned short* xb    = (unsigned short*)(ws + ((size_t)0 << 20));
  unsigned short* yb    = (unsigned short*)(ws + ((size_t)16 << 20));
  unsigned short* wkvt  = (unsigned short*)(ws + ((size_t)32 << 20));
  unsigned short* wqt   = (unsigned short*)(ws + ((size_t)36 << 20));
  unsigned short* wot   = (unsigned short*)(ws + ((size_t)38 << 20));
  unsigned short* kbuf  = (unsigned short*)(ws + ((size_t)40 << 20));
  unsigned short* vtbuf = (unsigned short*)(ws + ((size_t)56 << 20));
  unsigned short* qbuf  = (unsigned short*)(ws + ((size_t)72 << 20));
  unsigned short* valsb = (unsigned short*)(ws + ((size_t)88 << 20));
  float*          masks = (float*)        (ws + ((size_t)108 << 20));

  cast4<<<8192, 256, 0, stream>>>(x, xb, 2097152);
  cast4<<<8192, 256, 0, stream>>>(y, yb, 2097152);
  scale_mask<<<4096, 256, 0, stream>>>(mask, masks, 1048576);
  transpose_cast<<<dim3(64, 32), 256, 0, stream>>>(Wkv, wkvt, 1024, 2048);
  transpose_cast<<<dim3(32, 32), 256, 0, stream>>>(Wq, wqt, 1024, 1024);
  transpose_cast<<<dim3(32, 32), 256, 0, stream>>>(Wo, wot, 1024, 1024);

  // kv = x @ Wkv + bkv -> K[b,h,s,64], Vt[b,h,64,s]
  gemm128<1><<<dim3(16, 64), 256, 0, stream>>>(xb, wkvt, bkv, kbuf, vtbuf, 8192, 2048, 1024);
  // q = y @ Wq + bq -> Q[b,h,s,64] (pre-scaled)
  gemm128<2><<<dim3(8, 64), 256, 0, stream>>>(yb, wqt, bq, qbuf, nullptr, 8192, 1024, 1024);
  // attention -> vals [b,s,1024] bf16
  attn<<<1024, 256, 0, stream>>>(qbuf, kbuf, vtbuf, masks, valsb);
  // out = vals @ Wo + bo (fp32)
  gemm128<0><<<dim3(8, 64), 256, 0, stream>>>(valsb, wot, bo, (float*)d_out, nullptr, 8192, 1024, 1024);
}

// Round 4
// 463.030 us; speedup vs baseline: 1.4573x; 1.4573x over previous
//
#include <hip/hip_runtime.h>

#define LOG2E 1.44269504088896340736f
#define QSCALE 0.18033688011112042f  // 0.125 * LOG2E

typedef __attribute__((ext_vector_type(8))) short bf16x8;
typedef __attribute__((ext_vector_type(4))) float f32x4;

__device__ __forceinline__ unsigned short f2b(float f) {
  union { float f; unsigned int u; } x; x.f = f;
  return (unsigned short)((x.u + 0x8000u) >> 16);
}

// pack two fp32 -> two bf16 in 3 VALU ops
__device__ __forceinline__ unsigned int pk_bf16(float a, float b) {
  union { float f; unsigned int u; } xa, xb; xa.f = a; xb.f = b;
  return __builtin_amdgcn_perm(xb.u + 0x8000u, xa.u + 0x8000u, 0x07060302);
}

__device__ __forceinline__ void gld_lds16(const void* g, void* l) {
  __builtin_amdgcn_global_load_lds((const __attribute__((address_space(1))) void*)g,
                                   (__attribute__((address_space(3))) void*)l,
                                   16, 0, 0);
}

// ---------------- fused cast x,y fp32 -> bf16 ----------------
__global__ __launch_bounds__(256) void cast_xy(const float* __restrict__ x,
                                               const float* __restrict__ y,
                                               unsigned short* __restrict__ xb,
                                               unsigned short* __restrict__ yb) {
  int i = blockIdx.x * 256 + threadIdx.x;
  const float* in = x; unsigned short* out = xb;
  if (i >= 2097152) { in = y; out = yb; i -= 2097152; }
  float4 v = ((const float4*)in)[i];
  uint2 o;
  o.x = pk_bf16(v.x, v.y);
  o.y = pk_bf16(v.z, v.w);
  ((uint2*)out)[i] = o;
}

// ---------------- mask pre-scale: out = mask * log2(e), fp32 ----------------
__global__ __launch_bounds__(256) void scale_mask(const float* __restrict__ in,
                                                  float* __restrict__ out) {
  int i = blockIdx.x * 256 + threadIdx.x;
  f32x4 v = ((const f32x4*)in)[i];
  ((f32x4*)out)[i] = v * LOG2E;
}

// ---------------- fused transpose+cast of Wkv, Wq, Wo ----------------
__global__ __launch_bounds__(256) void transpose_cast_all(
    const float* __restrict__ Wkv, const float* __restrict__ Wq,
    const float* __restrict__ Wo, unsigned short* __restrict__ wkvt,
    unsigned short* __restrict__ wqt, unsigned short* __restrict__ wot) {
  __shared__ float t[32][33];
  int tb = blockIdx.x;
  const float* W; unsigned short* Wt; int N;
  if (tb < 2048)      { W = Wkv; Wt = wkvt; N = 2048; }
  else if (tb < 3072) { W = Wq;  Wt = wqt;  N = 1024; tb -= 2048; }
  else                { W = Wo;  Wt = wot;  N = 1024; tb -= 3072; }
  const int K = 1024;
  int tilesN = N >> 5;
  int nb = (tb % tilesN) * 32, kb = (tb / tilesN) * 32;
  int j = threadIdx.x & 31, i0 = threadIdx.x >> 5;
  #pragma unroll
  for (int p = 0; p < 4; ++p) {
    int i = i0 + p * 8;
    t[i][j] = W[(size_t)(kb + i) * N + nb + j];
  }
  __syncthreads();
  #pragma unroll
  for (int p = 0; p < 4; ++p) {
    int i = i0 + p * 8;
    Wt[(size_t)(nb + i) * K + kb + j] = f2b(t[j][i]);
  }
}

// ---------------- GEMM: C(MxN) = A(MxK) @ Bt(NxK)^T + bias ----------------
// XOR-granule-swizzled LDS (conflict-free b128 fragment reads).
// MODE 0: fp32 C out. MODE 1: kv -> K[b,h,s,64] + Vt[b,h,64,s]. MODE 2: q -> Q * QSCALE.
template <int MODE>
__global__ __launch_bounds__(256)
void gemm128(const unsigned short* __restrict__ A,
             const unsigned short* __restrict__ Bt,
             const float* __restrict__ bias,
             void* __restrict__ out0, void* __restrict__ out1,
             int M, int N, int K) {
  __shared__ __align__(16) unsigned short As[128 * 64];
  __shared__ __align__(16) unsigned short Bs[128 * 64];
  const int tid = threadIdx.x;
  const int bn = blockIdx.x, bm = blockIdx.y;
  const int wave = tid >> 6, lane = tid & 63;
  const int wm = (wave >> 1) * 64, wn = (wave & 1) * 64;
  const int lrow = lane & 15, quad = lane >> 4;
  const int sw = lrow & 7;  // fragment-read granule swizzle

  f32x4 acc[4][4];
  #pragma unroll
  for (int i = 0; i < 4; ++i)
    #pragma unroll
    for (int j = 0; j < 4; ++j)
      #pragma unroll
      for (int r = 0; r < 4; ++r) acc[i][j][r] = 0.f;

  const unsigned short* Ab = A + (size_t)(bm * 128) * K;
  const unsigned short* Bb = Bt + (size_t)(bn * 128) * K;

  for (int k0 = 0; k0 < K; k0 += 64) {
    #pragma unroll
    for (int i = 0; i < 4; ++i) {
      int e = i * 256 + tid;
      int row = e >> 3, gs = (e & 7) ^ (row & 7);
      gld_lds16(Ab + (size_t)row * K + k0 + gs * 8, &As[e * 8]);
    }
    #pragma unroll
    for (int i = 0; i < 4; ++i) {
      int e = i * 256 + tid;
      int row = e >> 3, gs = (e & 7) ^ (row & 7);
      gld_lds16(Bb + (size_t)row * K + k0 + gs * 8, &Bs[e * 8]);
    }
    __builtin_amdgcn_s_waitcnt(0);
    __syncthreads();
    #pragma unroll
    for (int ks = 0; ks < 2; ++ks) {
      bf16x8 af[4], bf[4];
      const int g = ((ks * 4 + quad) ^ sw) * 8;
      #pragma unroll
      for (int i = 0; i < 4; ++i)
        af[i] = *(const bf16x8*)&As[(wm + i * 16 + lrow) * 64 + g];
      #pragma unroll
      for (int j = 0; j < 4; ++j)
        bf[j] = *(const bf16x8*)&Bs[(wn + j * 16 + lrow) * 64 + g];
      #pragma unroll
      for (int i = 0; i < 4; ++i)
        #pragma unroll
        for (int j = 0; j < 4; ++j)
          acc[i][j] = __builtin_amdgcn_mfma_f32_16x16x32_bf16(af[i], bf[j], acc[i][j], 0, 0, 0);
    }
    __syncthreads();
  }

  const int col0 = bn * 128 + wn;
  #pragma unroll
  for (int i = 0; i < 4; ++i) {
    const int row0 = bm * 128 + wm + i * 16 + quad * 4;
    const int b = row0 >> 11, s0 = row0 & 2047;
    #pragma unroll
    for (int j = 0; j < 4; ++j) {
      const int cc = j * 16 + lrow;
      const float bv = bias[col0 + cc];
      float v0 = acc[i][j][0] + bv, v1 = acc[i][j][1] + bv;
      float v2 = acc[i][j][2] + bv, v3 = acc[i][j][3] + bv;
      if (MODE == 0) {
        float* C = (float*)out0;
        size_t off = (size_t)row0 * N + col0 + cc;
        C[off] = v0; C[off + N] = v1; C[off + 2 * N] = v2; C[off + 3 * N] = v3;
      } else if (MODE == 1) {
        const int h = col0 >> 7;
        if ((col0 & 64) == 0) {  // K half: K[b,h,s,64]
          unsigned short* Kb = (unsigned short*)out0;
          size_t base = ((size_t)(b * 16 + h) * 2048 + s0) * 64 + cc;
          Kb[base] = f2b(v0); Kb[base + 64] = f2b(v1);
          Kb[base + 128] = f2b(v2); Kb[base + 192] = f2b(v3);
        } else {                 // V half: Vt[b,h,64,s]
          unsigned short* Vt = (unsigned short*)out1;
          size_t base = ((size_t)(b * 16 + h) * 64 + cc) * 2048 + s0;
          uint2 p; p.x = pk_bf16(v0, v1); p.y = pk_bf16(v2, v3);
          *(uint2*)&Vt[base] = p;
        }
      } else {  // MODE 2: Q[b,h,s,64] pre-scaled
        v0 *= QSCALE; v1 *= QSCALE; v2 *= QSCALE; v3 *= QSCALE;
        const int h = col0 >> 6;
        unsigned short* Qb = (unsigned short*)out0;
        size_t base = ((size_t)(b * 16 + h) * 2048 + s0) * 64 + cc;
        Qb[base] = f2b(v0); Qb[base + 64] = f2b(v1);
        Qb[base + 128] = f2b(v2); Qb[base + 192] = f2b(v3);
      }
    }
  }
}

// ---------------- flash attention v4: LDS-staged + swizzle + slim softmax ----
// grid 1024; 2 qt per XCD (mask L2-resident). 4 waves x 32 q-cols.
// S^T = K Q^T with mask*log2e as C-init; exp2 (no max-tracking); P roundtrip
// through wave-private LDS (pitch 72); O^T = V^T P^T.
__global__ __launch_bounds__(256)
void attn(const unsigned short* __restrict__ Qbuf,
          const unsigned short* __restrict__ Kbuf,
          const unsigned short* __restrict__ Vtbuf,
          const float* __restrict__ masks,   // mask * log2e, fp32
          unsigned short* __restrict__ vals) {
  const int blk = blockIdx.x;
  const int xcd = blk & 7, slot = blk >> 3;       // slot 0..127
  const int qt = xcd * 2 + (slot >> 6);           // 2 qt values per XCD
  const int hb = slot & 63;
  const int b = hb >> 4, h = hb & 15;
  const int tid = threadIdx.x, lane = tid & 63, w = tid >> 6;
  const int lrow = lane & 15, quad = lane >> 4;
  const int sw = lrow & 7;

  __shared__ __align__(16) unsigned short Ks[64 * 64];   // [key][d] swizzled
  __shared__ __align__(16) unsigned short Vs[64 * 64];   // [d][key] swizzled
  __shared__ __align__(16) unsigned short Ps[128 * 72];  // Q staging (pitch 64) then P^T (pitch 72)

  const unsigned short* qp = Qbuf + ((size_t)(b * 16 + h) * 2048 + qt * 128) * 64;
  const unsigned short* kp = Kbuf + (size_t)(b * 16 + h) * 2048 * 64;
  const unsigned short* vp = Vtbuf + (size_t)(b * 16 + h) * 64 * 2048;
  const float* mp = masks + (size_t)(qt * 128 + w * 32) * 2048;

  // stage Q (128x64) swizzled into Ps (pitch 64)
  #pragma unroll
  for (int i = 0; i < 4; ++i) {
    int e = i * 256 + tid;
    int row = e >> 3, gs = (e & 7) ^ (row & 7);
    gld_lds16(qp + (size_t)row * 64 + gs * 8, &Ps[e * 8]);
  }
  __builtin_amdgcn_s_waitcnt(0);
  __syncthreads();
  bf16x8 qf[2][2];  // [iq][ks]  B-operand: n=q, k=d
  #pragma unroll
  for (int iq = 0; iq < 2; ++iq)
    #pragma unroll
    for (int ks = 0; ks < 2; ++ks)
      qf[iq][ks] = *(const bf16x8*)&Ps[(w * 32 + iq * 16 + lrow) * 64 + ((ks * 4 + quad) ^ sw) * 8];
  __syncthreads();  // all Q reads done before Ps is reused for P^T

  f32x4 o_acc[4][2];  // O^T: d = id*16+quad*4+r, q = iq*16+lrow
  #pragma unroll
  for (int id = 0; id < 4; ++id)
    #pragma unroll
    for (int iq = 0; iq < 2; ++iq)
      #pragma unroll
      for (int r = 0; r < 4; ++r) o_acc[id][iq][r] = 0.f;
  float lsum[2] = {0.f, 0.f};

  for (int kt = 0; kt < 32; ++kt) {
    __syncthreads();  // previous tile's Ks/Vs reads complete
    #pragma unroll
    for (int i = 0; i < 2; ++i) {  // K tile
      int e = i * 256 + tid;
      int row = e >> 3, gs = (e & 7) ^ (row & 7);
      gld_lds16(kp + (size_t)(kt * 64 + row) * 64 + gs * 8, &Ks[e * 8]);
    }
    #pragma unroll
    for (int i = 0; i < 2; ++i) {  // V^T tile
      int e = i * 256 + tid;
      int row = e >> 3, gs = (e & 7) ^ (row & 7);
      gld_lds16(vp + (size_t)row * 2048 + kt * 64 + gs * 8, &Vs[e * 8]);
    }
    __builtin_amdgcn_s_waitcnt(0);
    __syncthreads();

    // z init = pre-scaled mask (cached float4 loads)
    f32x4 z[4][2];
    #pragma unroll
    for (int ik = 0; ik < 4; ++ik)
      #pragma unroll
      for (int iq = 0; iq < 2; ++iq)
        z[ik][iq] = *(const f32x4*)(mp + (size_t)(iq * 16 + lrow) * 2048 + kt * 64 + ik * 16 + quad * 4);

    // S^T = K (Q*c)^T + mask*log2e
    #pragma unroll
    for (int ks = 0; ks < 2; ++ks) {
      bf16x8 kf[4];
      const int g = ((ks * 4 + quad) ^ sw) * 8;
      #pragma unroll
      for (int ik = 0; ik < 4; ++ik)
        kf[ik] = *(const bf16x8*)&Ks[(ik * 16 + lrow) * 64 + g];
      #pragma unroll
      for (int ik = 0; ik < 4; ++ik)
        #pragma unroll
        for (int iq = 0; iq < 2; ++iq)
          z[ik][iq] = __builtin_amdgcn_mfma_f32_16x16x32_bf16(kf[ik], qf[iq][ks], z[ik][iq], 0, 0, 0);
    }

    // exp2, l partials, pack P^T -> wave-private LDS (pitch 72)
    #pragma unroll
    for (int ik = 0; ik < 4; ++ik)
      #pragma unroll
      for (int iq = 0; iq < 2; ++iq) {
        float e0 = exp2f(z[ik][iq][0]), e1 = exp2f(z[ik][iq][1]);
        float e2 = exp2f(z[ik][iq][2]), e3 = exp2f(z[ik][iq][3]);
        lsum[iq] += (e0 + e1) + (e2 + e3);
        uint2 p;
        p.x = pk_bf16(e0, e1);
        p.y = pk_bf16(e2, e3);
        *(uint2*)&Ps[(w * 32 + iq * 16 + lrow) * 72 + ik * 16 + quad * 4] = p;
      }
    __builtin_amdgcn_s_waitcnt(0xC07F);  // lgkmcnt(0): our Ps writes -> our reads

    // O^T += V^T P^T
    #pragma unroll
    for (int ks = 0; ks < 2; ++ks) {
      bf16x8 vf[4], pf[2];
      const int g = ((ks * 4 + quad) ^ sw) * 8;
      #pragma unroll
      for (int id = 0; id < 4; ++id)
        vf[id] = *(const bf16x8*)&Vs[(id * 16 + lrow) * 64 + g];
      #pragma unroll
      for (int iq = 0; iq < 2; ++iq)
        pf[iq] = *(const bf16x8*)&Ps[(w * 32 + iq * 16 + lrow) * 72 + ks * 32 + quad * 8];
      #pragma unroll
      for (int id = 0; id < 4; ++id)
        #pragma unroll
        for (int iq = 0; iq < 2; ++iq)
          o_acc[id][iq] = __builtin_amdgcn_mfma_f32_16x16x32_bf16(vf[id], pf[iq], o_acc[id][iq], 0, 0, 0);
    }
  }

  // normalize + store O^T
  unsigned short* ob = vals + (size_t)(b * 2048 + qt * 128 + w * 32) * 1024 + h * 64;
  #pragma unroll
  for (int iq = 0; iq < 2; ++iq) {
    float s = lsum[iq];
    s += __shfl_xor(s, 16);
    s += __shfl_xor(s, 32);
    float inv = 1.f / s;
    #pragma unroll
    for (int id = 0; id < 4; ++id) {
      uint2 p;
      p.x = pk_bf16(o_acc[id][iq][0] * inv, o_acc[id][iq][1] * inv);
      p.y = pk_bf16(o_acc[id][iq][2] * inv, o_acc[id][iq][3] * inv);
      *(uint2*)&ob[(size_t)(iq * 16 + lrow) * 1024 + id * 16 + quad * 4] = p;
    }
  }
}

extern "C" void kernel_launch(void* const* d_in, const int* in_sizes, int n_in,
                              void* d_out, int out_size, void* d_ws, size_t ws_size,
                              hipStream_t stream) {
  const float* x    = (const float*)d_in[0];
  const float* y    = (const float*)d_in[1];
  const float* mask = (const float*)d_in[2];
  const float* Wkv  = (const float*)d_in[3];
  const float* bkv  = (const float*)d_in[4];
  const float* Wq   = (const float*)d_in[5];
  const float* bq   = (const float*)d_in[6];
  const float* Wo   = (const float*)d_in[7];
  const float* bo   = (const float*)d_in[8];

  char* ws = (char*)d_ws;
  unsigned short* xb    = (unsigned short*)(ws + ((size_t)0 << 20));
  unsigned short* yb    = (unsigned short*)(ws + ((size_t)16 << 20));
  unsigned short* wkvt  = (unsigned short*)(ws + ((size_t)32 << 20));
  unsigned short* wqt   = (unsigned short*)(ws + ((size_t)36 << 20));
  unsigned short* wot   = (unsigned short*)(ws + ((size_t)38 << 20));
  unsigned short* kbuf  = (unsigned short*)(ws + ((size_t)40 << 20));
  unsigned short* vtbuf = (unsigned short*)(ws + ((size_t)56 << 20));
  unsigned short* qbuf  = (unsigned short*)(ws + ((size_t)72 << 20));
  unsigned short* valsb = (unsigned short*)(ws + ((size_t)88 << 20));
  float*          masks = (float*)        (ws + ((size_t)108 << 20));

  cast_xy<<<16384, 256, 0, stream>>>(x, y, xb, yb);
  scale_mask<<<4096, 256, 0, stream>>>(mask, masks);
  transpose_cast_all<<<4096, 256, 0, stream>>>(Wkv, Wq, Wo, wkvt, wqt, wot);

  // kv = x @ Wkv + bkv -> K[b,h,s,64], Vt[b,h,64,s]
  gemm128<1><<<dim3(16, 64), 256, 0, stream>>>(xb, wkvt, bkv, kbuf, vtbuf, 8192, 2048, 1024);
  // q = y @ Wq + bq -> Q[b,h,s,64] (pre-scaled)
  gemm128<2><<<dim3(8, 64), 256, 0, stream>>>(yb, wqt, bq, qbuf, nullptr, 8192, 1024, 1024);
  // attention -> vals [b,s,1024] bf16
  attn<<<1024, 256, 0, stream>>>(qbuf, kbuf, vtbuf, masks, valsb);
  // out = vals @ Wo + bo (fp32)
  gemm128<0><<<dim3(8, 64), 256, 0, stream>>>(valsb, wot, bo, (float*)d_out, nullptr, 8192, 1024, 1024);
}